// Round 12
// baseline (936.311 us; speedup 1.0000x reference)
//
#include <hip/hip_runtime.h>
#include <hip/hip_cooperative_groups.h>

namespace cg = cooperative_groups;

// RGCN 2-layer hetero graph conv. fp32 I/O, bf16 MFMA compute.
// R12: entire CSR build + prep collapsed into ONE cooperative kernel (6 phases
// separated by grid.sync() instead of kernel boundaries; phases grid-stride
// over virtual blocks). Removes 5 launch gaps + idle tails. Gather (memory
// floor, ~8.2 TB/s effective) and GEMMs (streaming BW floor) unchanged.

#define DI 128
#define NP 100000
#define NA 50000
#define EPB 4096
#define MAXBIN 391

typedef short s8v __attribute__((ext_vector_type(8)));
typedef float f32x4 __attribute__((ext_vector_type(4)));

__device__ __forceinline__ unsigned short bf16_rne(float f) {
  unsigned int fb = __float_as_uint(f);
  fb += 0x7FFFu + ((fb >> 16) & 1u);
  return (unsigned short)(fb >> 16);
}

// ==== arg structs ====
struct R3Args {
  const int* src[3]; const int* dst[3];
  int* bh[3]; int* bhs[3];
  unsigned int* tmp[3];
  int* bkt[3]; int* cnt[3]; int* rs[3];
  int E[3]; int N[3]; int nbin[3]; int NB[3];
};
struct S3Args {
  const int* cnt[3]; int* bsum[3]; int* rs[3];
  int n[3]; int nb[3];
};
struct WArgs {
  const float* w[10];
  unsigned short* wf[10];
};
struct CoopArgs {
  R3Args ra;
  S3Args sa;
  WArgs wa;
  const float* Xp; unsigned short* Yp; int n4p;
  const float* Xa; unsigned short* Ya; int n4a;
  int maxNB, maxnb, maxbin;
  int nCvt;          // cvt virtual blocks
};

// ==== cooperative CSR + prep mega-kernel ====
// Phases: 1) s1 hist + warrange + cvt  2) blocksum  3) partials
//         4) scanwrite  5) x1 scatter  6) p2 buckets
__global__ __launch_bounds__(256) void coop_csr_k(CoopArgs a) {
  cg::grid_group grid = cg::this_grid();
  __shared__ int lds[768];
  const int t = threadIdx.x;
  const int GB = gridDim.x;

  // ---- phase 1: s1 per-chunk hist (LDS) + weight rearrange + fp32->bf16 cvt ----
  {
    const int vb_s1 = 3 * a.maxNB;
    const int vbTot = vb_s1 + 80 + a.nCvt;
    for (int vb = blockIdx.x; vb < vbTot; vb += GB) {
      if (vb < vb_s1) {
        int y = vb / a.maxNB, blk = vb % a.maxNB;
        int NB = a.ra.NB[y];
        if (blk < NB) {
          int nbin = a.ra.nbin[y];
          for (int i = t; i < nbin; i += 256) lds[i] = 0;
          __syncthreads();
          int e0 = blk * EPB, e1 = min(e0 + EPB, a.ra.E[y]);
          const int* dst = a.ra.dst[y];
          for (int e = e0 + t; e < e1; e += 256) atomicAdd(&lds[dst[e] >> 8], 1);
          __syncthreads();
          int* bh = a.ra.bh[y];
          for (int i = t; i < nbin; i += 256) bh[i * NB + blk] = lds[i];
          __syncthreads();  // LDS reused next iteration
        }
      } else if (vb < vb_s1 + 80) {
        int b = vb - vb_s1;
        int widx = b >> 3;
        int OUTi = (widx < 5) ? 128 : 64;
        int CF = OUTi / 16;
        int nt = 4 * CF * 64;
        int tg = (b & 7) * 256 + t;
        if (tg < nt) {
          int lane = tg & 63, tmp2 = tg >> 6;
          int cf = tmp2 % CF, kc = tmp2 / CF;
          int k0 = kc * 32 + (lane >> 4) * 8;
          int c  = cf * 16 + (lane & 15);
          const float* w = a.wa.w[widx];
          s8v v;
          #pragma unroll
          for (int i = 0; i < 8; ++i) v[i] = (short)bf16_rne(w[(k0 + i) * OUTi + c]);
          *(reinterpret_cast<s8v*>(a.wa.wf[widx]) + tg) = v;
        }
      } else {
        int i = (vb - vb_s1 - 80) * 256 + t;
        const float* X; unsigned short* Y;
        bool ok = true;
        if (i < a.n4p) { X = a.Xp; Y = a.Yp; }
        else { i -= a.n4p; if (i >= a.n4a) ok = false; else { X = a.Xa; Y = a.Ya; } }
        if (ok) {
          float4 f = reinterpret_cast<const float4*>(X)[i];
          ushort4 o;
          o.x = bf16_rne(f.x); o.y = bf16_rne(f.y); o.z = bf16_rne(f.z); o.w = bf16_rne(f.w);
          reinterpret_cast<ushort4*>(Y)[i] = o;
        }
      }
    }
  }
  grid.sync();

  // ---- phase 2: blocksum (bh chunks of 1024 -> bsum) ----
  {
    const int vbTot = 3 * a.maxnb;
    for (int vb = blockIdx.x; vb < vbTot; vb += GB) {
      int y = vb / a.maxnb, blk = vb % a.maxnb;
      int n = a.sa.n[y];
      if (blk * 1024 < n) {
        int base = blk * 1024 + t * 4;
        int s = 0;
        #pragma unroll
        for (int i = 0; i < 4; ++i) { int idx = base + i; if (idx < n) s += a.sa.cnt[y][idx]; }
        lds[t] = s; __syncthreads();
        #pragma unroll
        for (int o = 128; o > 0; o >>= 1) { if (t < o) lds[t] += lds[t + o]; __syncthreads(); }
        if (t == 0) a.sa.bsum[y][blk] = lds[0];
        __syncthreads();
      }
    }
  }
  grid.sync();

  // ---- phase 3: exclusive scan of bsum (3 virtual blocks, nb <= 256) ----
  {
    for (int vb = blockIdx.x; vb < 3; vb += GB) {
      int nb = a.sa.nb[vb];
      int v = (t < nb) ? a.sa.bsum[vb][t] : 0;
      lds[t] = v; __syncthreads();
      int acc = v;
      for (int o = 1; o < 256; o <<= 1) {
        int u = (t >= o) ? lds[t - o] : 0;
        __syncthreads();
        acc += u; lds[t] = acc;
        __syncthreads();
      }
      if (t < nb) a.sa.bsum[vb][t] = acc - v;  // exclusive
      __syncthreads();
    }
  }
  grid.sync();

  // ---- phase 4: scanwrite (bh -> bhs with bsum offsets) ----
  {
    const int vbTot = 3 * a.maxnb;
    for (int vb = blockIdx.x; vb < vbTot; vb += GB) {
      int y = vb / a.maxnb, blk = vb % a.maxnb;
      int n = a.sa.n[y];
      if (blk * 1024 < n) {
        int base = blk * 1024 + t * 4;
        int v[4]; int s = 0;
        #pragma unroll
        for (int i = 0; i < 4; ++i) { int idx = base + i; v[i] = (idx < n) ? a.sa.cnt[y][idx] : 0; s += v[i]; }
        lds[t] = s; __syncthreads();
        int inc = s;
        for (int o = 1; o < 256; o <<= 1) {
          int u = (t >= o) ? lds[t - o] : 0;
          __syncthreads();
          inc += u; lds[t] = inc;
          __syncthreads();
        }
        int p = a.sa.bsum[y][blk] + inc - s;
        #pragma unroll
        for (int i = 0; i < 4; ++i) { int idx = base + i; if (idx < n) { a.sa.rs[y][idx] = p; p += v[i]; } }
        __syncthreads();
      }
    }
  }
  grid.sync();

  // ---- phase 5: x1 scatter into coarse buckets (LDS cursors) ----
  {
    const int vbTot = 3 * a.maxNB;
    for (int vb = blockIdx.x; vb < vbTot; vb += GB) {
      int y = vb / a.maxNB, blk = vb % a.maxNB;
      int NB = a.ra.NB[y];
      if (blk < NB) {
        int nbin = a.ra.nbin[y];
        const int* bhs = a.ra.bhs[y];
        for (int i = t; i < nbin; i += 256) lds[i] = bhs[i * NB + blk];
        __syncthreads();
        int e0 = blk * EPB, e1 = min(e0 + EPB, a.ra.E[y]);
        const int* dst = a.ra.dst[y];
        const int* src = a.ra.src[y];
        unsigned int* tmp = a.ra.tmp[y];
        for (int e = e0 + t; e < e1; e += 256) {
          int d = dst[e];
          int pos = atomicAdd(&lds[d >> 8], 1);
          tmp[pos] = ((unsigned int)(d & 255) << 24) | (unsigned int)src[e];
        }
        __syncthreads();
      }
    }
  }
  grid.sync();

  // ---- phase 6: p2 per-bucket hist+scan -> cnt, rs, bkt (byte offsets) ----
  {
    int* hist = lds; int* scn = lds + 256; int* cursor = lds + 512;
    const int vbTot = 3 * a.maxbin;
    for (int vb = blockIdx.x; vb < vbTot; vb += GB) {
      int y = vb / a.maxbin, bin = vb % a.maxbin;
      if (bin < a.ra.nbin[y]) {
        hist[t] = 0;
        __syncthreads();
        const int* bhs = a.ra.bhs[y];
        int NB = a.ra.NB[y];
        int base = bhs[bin * NB];
        int end  = (bin + 1 < a.ra.nbin[y]) ? bhs[(bin + 1) * NB] : a.ra.E[y];
        const unsigned int* tmp = a.ra.tmp[y];
        for (int i = base + t; i < end; i += 256)
          atomicAdd(&hist[tmp[i] >> 24], 1);
        __syncthreads();
        int v = hist[t];
        scn[t] = v; __syncthreads();
        int acc = v;
        for (int o = 1; o < 256; o <<= 1) {
          int u = (t >= o) ? scn[t - o] : 0;
          __syncthreads();
          acc += u; scn[t] = acc;
          __syncthreads();
        }
        int ex = acc - v;
        cursor[t] = ex;
        int d = bin * 256 + t;
        if (d < a.ra.N[y]) { a.ra.cnt[y][d] = v; a.ra.rs[y][d] = base + ex; }
        __syncthreads();
        int* bkt = a.ra.bkt[y];
        for (int i = base + t; i < end; i += 256) {
          unsigned int p = tmp[i];
          int pos = atomicAdd(&cursor[p >> 24], 1);
          bkt[base + pos] = (int)((p & 0xFFFFFFu) << 8);  // BYTE offset: src*256
        }
        __syncthreads();
      }
    }
  }
}

// ==== gather-max: 16 lanes/row (dwordx4), 4 rows/wave, 16 rows/block, 3-way y ====
struct G3Args {
  const int* cnt[3]; const int* rs[3]; const int* bkt[3];
  const unsigned short* X[3]; unsigned short* S[3];
  int N[3];
};

__global__ __launch_bounds__(256) void gather3_k(G3Args a) {
  const int y = blockIdx.y;
  const int lane = threadIdx.x & 63;
  const int wave = threadIdx.x >> 6;
  const int g = lane >> 4, lg = lane & 15;
  const int d = blockIdx.x * 16 + wave * 4 + g;
  if (d >= a.N[y]) return;

  unsigned short* So = a.S[y] + (size_t)d * DI + lg * 8;
  const int deg = a.cnt[y][d];
  if (deg == 0) {
    uint4 z; z.x = z.y = z.z = z.w = 0u;
    *reinterpret_cast<uint4*>(So) = z;
    return;
  }
  const int* bp = a.bkt[y] + a.rs[y][d];
  const char* Xb = reinterpret_cast<const char*>(a.X[y]) + lg * 16;

  float ml[4], mh[4];
  #pragma unroll
  for (int j = 0; j < 4; ++j) { ml[j] = -3.4e38f; mh[j] = -3.4e38f; }

  int s0 = bp[0];
  for (int e = 0; e < deg; e += 4) {
    int s1 = (e + 1 < deg) ? bp[e + 1] : s0;   // branchless tail: re-max row 0
    int s2 = (e + 2 < deg) ? bp[e + 2] : s0;
    int s3 = (e + 3 < deg) ? bp[e + 3] : s0;
    int sn = (e + 4 < deg) ? bp[e + 4] : s0;
    uint4 r0 = *reinterpret_cast<const uint4*>(Xb + s0);
    uint4 r1 = *reinterpret_cast<const uint4*>(Xb + s1);
    uint4 r2 = *reinterpret_cast<const uint4*>(Xb + s2);
    uint4 r3 = *reinterpret_cast<const uint4*>(Xb + s3);
    unsigned int w0[4] = {r0.x, r0.y, r0.z, r0.w};
    unsigned int w1[4] = {r1.x, r1.y, r1.z, r1.w};
    unsigned int w2[4] = {r2.x, r2.y, r2.z, r2.w};
    unsigned int w3[4] = {r3.x, r3.y, r3.z, r3.w};
    #pragma unroll
    for (int j = 0; j < 4; ++j) {
      float tl = fmaxf(fmaxf(__uint_as_float(w0[j] << 16), __uint_as_float(w1[j] << 16)),
                       __uint_as_float(w2[j] << 16));
      ml[j] = fmaxf(fmaxf(ml[j], __uint_as_float(w3[j] << 16)), tl);
      // high halves: RAW word as float (low bits perturb < 1 ulp of hi bf16)
      float th = fmaxf(fmaxf(__uint_as_float(w0[j]), __uint_as_float(w1[j])),
                       __uint_as_float(w2[j]));
      mh[j] = fmaxf(fmaxf(mh[j], __uint_as_float(w3[j])), th);
    }
    s0 = sn;
  }
  uint4 o;
  o.x = (__float_as_uint(ml[0]) >> 16) | (__float_as_uint(mh[0]) & 0xFFFF0000u);
  o.y = (__float_as_uint(ml[1]) >> 16) | (__float_as_uint(mh[1]) & 0xFFFF0000u);
  o.z = (__float_as_uint(ml[2]) >> 16) | (__float_as_uint(mh[2]) & 0xFFFF0000u);
  o.w = (__float_as_uint(ml[3]) >> 16) | (__float_as_uint(mh[3]) & 0xFFFF0000u);
  *reinterpret_cast<uint4*>(So) = o;
}

// ==== fused GEMM pair ====
template<int CF>
__device__ __forceinline__ void mfma_accum(const unsigned short* __restrict__ A,
                                           const unsigned short* __restrict__ W,
                                           f32x4* acc, size_t arow, int lane, int half) {
  const s8v* a = reinterpret_cast<const s8v*>(A + arow * DI + half * 8);
  const s8v* w = reinterpret_cast<const s8v*>(W) + lane;
  #pragma unroll
  for (int kc = 0; kc < 4; ++kc) {
    s8v av = a[kc * 4];
    #pragma unroll
    for (int cf = 0; cf < CF; ++cf)
      acc[cf] = __builtin_amdgcn_mfma_f32_16x16x32_bf16(av, w[(kc * CF + cf) * 64], acc[cf], 0, 0, 0);
  }
}

struct GemmPairArgs {
  const unsigned short *A0[2], *W0[2], *A1[2], *W1[2], *A2, *W2;
  const float* bias[2];
  void* out[2];
  int N[2];
  int blocks0;
};

template<int OUT, bool RELU, bool OUT_BF16>
__global__ __launch_bounds__(256) void gemm_pair_k(GemmPairArgs g) {
  constexpr int CF = OUT / 16;
  const int p = (blockIdx.x >= (unsigned)g.blocks0) ? 1 : 0;
  const int brow = blockIdx.x - (p ? g.blocks0 : 0);
  const int N = g.N[p];
  const int lane = threadIdx.x & 63;
  const int wave = threadIdx.x >> 6;
  const int row0 = brow * 64 + wave * 16;
  if (row0 >= N) return;
  const int rl = lane & 15, half = lane >> 4;
  const size_t arow = (size_t)(row0 + rl);

  f32x4 acc[CF];
  #pragma unroll
  for (int i = 0; i < CF; ++i) acc[i] = f32x4{0.f, 0.f, 0.f, 0.f};

  mfma_accum<CF>(g.A0[p], g.W0[p], acc, arow, lane, half);
  mfma_accum<CF>(g.A1[p], g.W1[p], acc, arow, lane, half);
  if (!p) mfma_accum<CF>(g.A2, g.W2, acc, arow, lane, half);

  const float* bias = g.bias[p];
  #pragma unroll
  for (int cf = 0; cf < CF; ++cf) {
    float bv = bias[cf * 16 + rl];
    #pragma unroll
    for (int j = 0; j < 4; ++j) {
      int r = row0 + half * 4 + j;
      if (r >= N) continue;
      float v = acc[cf][j] + bv;
      if (RELU) v = v > 0.f ? v : 0.f;
      size_t idx = (size_t)r * OUT + cf * 16 + rl;
      if (OUT_BF16) ((unsigned short*)g.out[p])[idx] = bf16_rne(v);
      else          __builtin_nontemporal_store(v, (float*)g.out[p] + idx);
    }
  }
}

extern "C" void kernel_launch(void* const* d_in, const int* in_sizes, int n_in,
                              void* d_out, int out_size, void* d_ws, size_t ws_size,
                              hipStream_t stream) {
  const float* xp = (const float*)d_in[0];
  const float* xa = (const float*)d_in[1];
  const int* wsrc = (const int*)d_in[2];
  const int* wdst = (const int*)d_in[3];
  const int* csrc = (const int*)d_in[4];
  const int* cdst = (const int*)d_in[5];
  const int* bsrc = (const int*)d_in[6];
  const int* bdst = (const int*)d_in[7];
  const int Ew = in_sizes[2], Ec = in_sizes[4], Eb = in_sizes[6];

  const float* w1w  = (const float*)d_in[8];
  const float* w1c  = (const float*)d_in[9];
  const float* w1wb = (const float*)d_in[10];
  const float* w1rp = (const float*)d_in[11];
  const float* b1rp = (const float*)d_in[12];
  const float* w1ra = (const float*)d_in[13];
  const float* b1ra = (const float*)d_in[14];
  const float* w2w  = (const float*)d_in[15];
  const float* w2c  = (const float*)d_in[16];
  const float* w2wb = (const float*)d_in[17];
  const float* w2rp = (const float*)d_in[18];
  const float* b2rp = (const float*)d_in[19];
  const float* w2ra = (const float*)d_in[20];
  const float* b2ra = (const float*)d_in[21];

  // ---- workspace layout (bytes) ----
  char* ws = (char*)d_ws;
  unsigned short* xpb = (unsigned short*)(ws + 0);           // 25,600,000
  unsigned short* xab = (unsigned short*)(ws + 25600000);    // 12,800,000
  unsigned short* hp  = (unsigned short*)(ws + 38400000);    // 25,600,000
  unsigned short* ha  = (unsigned short*)(ws + 64000000);    // 12,800,000
  unsigned short* S_w = (unsigned short*)(ws + 76800000);    // 25,600,000
  unsigned short* S_c = (unsigned short*)(ws + 102400000);   // 25,600,000
  unsigned short* S_b = (unsigned short*)(ws + 128000000);   // 12,800,000
  int* bkt_w = (int*)(ws + 140800000);                       // 3,200,000
  int* bkt_c = (int*)(ws + 144000000);                       // 3,200,000
  int* bkt_b = (int*)(ws + 147200000);                       // 3,200,000
  int* cnt_w = (int*)(ws + 150400000);                       // 400,000
  int* cnt_c = (int*)(ws + 150800000);                       // 400,000
  int* cnt_b = (int*)(ws + 151200000);                       // 200,000
  int* rs_w  = (int*)(ws + 151400000);                       // 400,000
  int* rs_c  = (int*)(ws + 151800000);                       // 400,000
  int* rs_b  = (int*)(ws + 152200000);                       // 200,000
  int* bsum_w = (int*)(ws + 152400000);                      // 4,096
  int* bsum_c = (int*)(ws + 152404096);                      // 4,096
  int* bsum_b = (int*)(ws + 152408192);                      // 4,096
  unsigned short* wf = (unsigned short*)(ws + 152412288);    // 245,760
  unsigned int* tmp_w = (unsigned int*)(ws + 152660000);     // 3,200,000
  unsigned int* tmp_c = (unsigned int*)(ws + 155860000);     // 3,200,000
  unsigned int* tmp_b = (unsigned int*)(ws + 159060000);     // 3,200,000
  // bh/bhs carved from S_w region (dead until first gather, which is after coop)
  int* bh_w  = (int*)(ws + 76800000);
  int* bh_c  = (int*)(ws + 77110000);
  int* bh_b  = (int*)(ws + 77420000);
  int* bhs_w = (int*)(ws + 77580000);
  int* bhs_c = (int*)(ws + 77890000);
  int* bhs_b = (int*)(ws + 78200000);

  unsigned short* WF[10];
  size_t off = 0;
  for (int i = 0; i < 10; ++i) {
    WF[i] = wf + off;
    off += (i < 5) ? (size_t)128 * 128 : (size_t)128 * 64;
  }

  float* outP = (float*)d_out;              // 100000 x 64 fp32
  float* outA = outP + (size_t)NP * 64;     // 50000 x 64 fp32

  const int gP = (NP + 63) / 64, gA = (NA + 63) / 64;  // 1563, 782
  const int gG = (NP + 15) / 16;                       // 6250

  // ---- radix CSR args ----
  R3Args ra;
  ra.src[0] = wsrc; ra.dst[0] = wdst; ra.E[0] = Ew; ra.N[0] = NP;
  ra.src[1] = csrc; ra.dst[1] = cdst; ra.E[1] = Ec; ra.N[1] = NP;
  ra.src[2] = bsrc; ra.dst[2] = bdst; ra.E[2] = Eb; ra.N[2] = NA;
  ra.bh[0] = bh_w; ra.bh[1] = bh_c; ra.bh[2] = bh_b;
  ra.bhs[0] = bhs_w; ra.bhs[1] = bhs_c; ra.bhs[2] = bhs_b;
  ra.tmp[0] = tmp_w; ra.tmp[1] = tmp_c; ra.tmp[2] = tmp_b;
  ra.bkt[0] = bkt_w; ra.bkt[1] = bkt_c; ra.bkt[2] = bkt_b;
  ra.cnt[0] = cnt_w; ra.cnt[1] = cnt_c; ra.cnt[2] = cnt_b;
  ra.rs[0] = rs_w; ra.rs[1] = rs_c; ra.rs[2] = rs_b;
  int maxNB = 0, maxnb = 0, maxbin = 0;
  for (int y = 0; y < 3; ++y) {
    ra.nbin[y] = (ra.N[y] + 255) >> 8;
    ra.NB[y] = (ra.E[y] + EPB - 1) / EPB;
    if (ra.NB[y] > maxNB) maxNB = ra.NB[y];
    if (ra.nbin[y] > maxbin) maxbin = ra.nbin[y];
  }
  S3Args sa;
  sa.bsum[0] = bsum_w; sa.bsum[1] = bsum_c; sa.bsum[2] = bsum_b;
  for (int y = 0; y < 3; ++y) {
    sa.cnt[y] = ra.bh[y]; sa.rs[y] = ra.bhs[y];
    sa.n[y] = ra.nbin[y] * ra.NB[y];
    sa.nb[y] = (sa.n[y] + 1023) / 1024;
    if (sa.nb[y] > maxnb) maxnb = sa.nb[y];
  }

  const int n4p = NP * DI / 4, n4a = NA * DI / 4;
  CoopArgs ca;
  ca.ra = ra;
  ca.sa = sa;
  const float* wsrcs[10] = {w1w, w1c, w1wb, w1rp, w1ra, w2w, w2c, w2wb, w2rp, w2ra};
  for (int i = 0; i < 10; ++i) { ca.wa.w[i] = wsrcs[i]; ca.wa.wf[i] = WF[i]; }
  ca.Xp = xp; ca.Yp = xpb; ca.n4p = n4p;
  ca.Xa = xa; ca.Ya = xab; ca.n4a = n4a;
  ca.maxNB = maxNB; ca.maxnb = maxnb; ca.maxbin = maxbin;
  ca.nCvt = (n4p + n4a + 255) / 256;

  G3Args g1, g2;
  for (int i = 0; i < 3; ++i) {
    g1.cnt[i] = g2.cnt[i] = (i == 0) ? cnt_w : (i == 1) ? cnt_c : cnt_b;
    g1.rs[i]  = g2.rs[i]  = (i == 0) ? rs_w  : (i == 1) ? rs_c  : rs_b;
    g1.bkt[i] = g2.bkt[i] = (i == 0) ? bkt_w : (i == 1) ? bkt_c : bkt_b;
    g1.S[i]   = g2.S[i]   = (i == 0) ? S_w   : (i == 1) ? S_c   : S_b;
    g1.N[i]   = g2.N[i]   = (i == 2) ? NA : NP;
  }
  g1.X[0] = xab; g1.X[1] = xpb; g1.X[2] = xpb;
  g2.X[0] = ha;  g2.X[1] = hp;  g2.X[2] = hp;

  GemmPairArgs p1, p2;
  p1.A0[0] = xpb; p1.W0[0] = WF[3]; p1.A1[0] = S_w; p1.W1[0] = WF[0]; p1.A2 = S_c; p1.W2 = WF[1];
  p1.bias[0] = b1rp; p1.out[0] = hp; p1.N[0] = NP;
  p1.A0[1] = xab; p1.W0[1] = WF[4]; p1.A1[1] = S_b; p1.W1[1] = WF[2];
  p1.bias[1] = b1ra; p1.out[1] = ha; p1.N[1] = NA;
  p1.blocks0 = gP;
  p2.A0[0] = hp; p2.W0[0] = WF[8]; p2.A1[0] = S_w; p2.W1[0] = WF[5]; p2.A2 = S_c; p2.W2 = WF[6];
  p2.bias[0] = b2rp; p2.out[0] = outP; p2.N[0] = NP;
  p2.A0[1] = ha; p2.W0[1] = WF[9]; p2.A1[1] = S_b; p2.W1[1] = WF[7];
  p2.bias[1] = b2ra; p2.out[1] = outA; p2.N[1] = NA;
  p2.blocks0 = gP;

  // ---- CSR build + prep: one cooperative dispatch (6 phases, grid.sync) ----
  {
    void* kargs[] = { (void*)&ca };
    hipLaunchCooperativeKernel((void*)coop_csr_k, dim3(1024), dim3(256),
                               kargs, 0, stream);
  }

  // ---- layer 1 ----
  gather3_k<<<dim3(gG, 3), 256, 0, stream>>>(g1);
  gemm_pair_k<128, true, true><<<gP + gA, 256, 0, stream>>>(p1);

  // ---- layer 2 ----
  gather3_k<<<dim3(gG, 3), 256, 0, stream>>>(g2);
  gemm_pair_k<64, false, false><<<gP + gA, 256, 0, stream>>>(p2);
}

// Round 13
// 377.746 us; speedup vs baseline: 2.4787x; 2.4787x over previous
//
#include <hip/hip_runtime.h>

// RGCN 2-layer hetero graph conv. fp32 I/O, bf16 MFMA compute.
// R13: REVERT R12's cooperative mega-kernel (grid.sync() costs ~107us each on
// 8-XCD gfx950 -> 702us for 60us of work; kernel boundaries are CHEAPER).
// Back to R11's proven split structure, with one cut: EPB 4096->16384 shrinks
// the coarse histogram 4x, letting the 3-kernel hierarchical scan collapse to
// ONE scan1_k dispatch (3 blocks x 1024 thr, serial 4096-chunks + carry).
// Prep chain: s1 -> scan1 -> x1 -> p2cvt (4 dispatches, was 6).

#define DI 128
#define NP 100000
#define NA 50000
#define EPB 16384
#define MAXBIN 391

typedef short s8v __attribute__((ext_vector_type(8)));
typedef float f32x4 __attribute__((ext_vector_type(4)));

__device__ __forceinline__ unsigned short bf16_rne(float f) {
  unsigned int fb = __float_as_uint(f);
  fb += 0x7FFFu + ((fb >> 16) & 1u);
  return (unsigned short)(fb >> 16);
}

// ==== radix CSR build (3 edge types via blockIdx.y) ====
struct R3Args {
  const int* src[3]; const int* dst[3];
  int* bh[3]; int* bhs[3];
  unsigned int* tmp[3];
  int* bkt[3]; int* cnt[3]; int* rs[3];
  int E[3]; int N[3]; int nbin[3]; int NB[3];
};

__global__ __launch_bounds__(256) void radix_s1_k(R3Args a) {
  int y = blockIdx.y, blk = blockIdx.x;
  int NB = a.NB[y];
  if (blk >= NB) return;
  __shared__ int hist[MAXBIN];
  int nbin = a.nbin[y];
  for (int i = threadIdx.x; i < nbin; i += 256) hist[i] = 0;
  __syncthreads();
  int e0 = blk * EPB, e1 = min(e0 + EPB, a.E[y]);
  const int* dst = a.dst[y];
  for (int e = e0 + threadIdx.x; e < e1; e += 256)
    atomicAdd(&hist[dst[e] >> 8], 1);
  __syncthreads();
  int* bh = a.bh[y];
  for (int i = threadIdx.x; i < nbin; i += 256) bh[i * NB + blk] = hist[i];
}

__global__ __launch_bounds__(256) void radix_x1_k(R3Args a) {
  int y = blockIdx.y, blk = blockIdx.x;
  int NB = a.NB[y];
  if (blk >= NB) return;
  __shared__ int cur[MAXBIN];
  int nbin = a.nbin[y];
  const int* bhs = a.bhs[y];
  for (int i = threadIdx.x; i < nbin; i += 256) cur[i] = bhs[i * NB + blk];
  __syncthreads();
  int e0 = blk * EPB, e1 = min(e0 + EPB, a.E[y]);
  const int* dst = a.dst[y];
  const int* src = a.src[y];
  unsigned int* tmp = a.tmp[y];
  for (int e = e0 + threadIdx.x; e < e1; e += 256) {
    int d = dst[e];
    int pos = atomicAdd(&cur[d >> 8], 1);
    tmp[pos] = ((unsigned int)(d & 255) << 24) | (unsigned int)src[e];
  }
}

// ==== single-dispatch exclusive scan: 3 blocks (one per edge type), 1024 thr,
// serial 4096-element chunks with LDS scan + running carry ====
struct S1Args {
  const int* cnt[3]; int* rs[3];
  int n[3];
};

__global__ __launch_bounds__(1024) void scan1_k(S1Args a) {
  const int y = blockIdx.x;
  const int n = a.n[y];
  const int t = threadIdx.x;
  __shared__ int sm[1024];
  __shared__ int carryS;
  if (t == 0) carryS = 0;
  __syncthreads();
  for (int base = 0; base < n; base += 4096) {
    int idx = base + t * 4;
    int v[4]; int s = 0;
    #pragma unroll
    for (int i = 0; i < 4; ++i) { int k = idx + i; v[i] = (k < n) ? a.cnt[y][k] : 0; s += v[i]; }
    sm[t] = s; __syncthreads();
    int acc = s;
    for (int o = 1; o < 1024; o <<= 1) {
      int u = (t >= o) ? sm[t - o] : 0;
      __syncthreads();
      acc += u; sm[t] = acc;
      __syncthreads();
    }
    int carry = carryS;
    int p = carry + acc - s;          // exclusive prefix for this thread's chunk
    #pragma unroll
    for (int i = 0; i < 4; ++i) { int k = idx + i; if (k < n) { a.rs[y][k] = p; p += v[i]; } }
    __syncthreads();                  // all reads of carryS done
    if (t == 1023) carryS = carry + acc;
    __syncthreads();
  }
}

// ---- weight rearrange args ----
struct WArgs {
  const float* w[10];
  unsigned short* wf[10];
};

// ==== merged: radix_p2 + weight rearrange + fp32->bf16 cvt ====
struct P2CArgs {
  R3Args ra;
  WArgs wa;
  const float* Xp; unsigned short* Yp; int n4p;
  const float* Xa; unsigned short* Ya; int n4a;
  int p2Blocks;   // 3 * maxbin
  int maxbin;
};

__global__ __launch_bounds__(256) void p2cvt_k(P2CArgs a) {
  int bid = blockIdx.x;
  int t = threadIdx.x;
  if (bid < a.p2Blocks) {
    // ---- radix pass 2: per coarse bucket, LDS hist+scan of low byte ----
    int y = bid / a.maxbin, bin = bid % a.maxbin;
    if (bin >= a.ra.nbin[y]) return;
    __shared__ int hist[256], scn[256], cursor[256];
    hist[t] = 0;
    __syncthreads();
    const int* bhs = a.ra.bhs[y];
    int NB = a.ra.NB[y];
    int base = bhs[bin * NB];
    int end  = (bin + 1 < a.ra.nbin[y]) ? bhs[(bin + 1) * NB] : a.ra.E[y];
    const unsigned int* tmp = a.ra.tmp[y];
    for (int i = base + t; i < end; i += 256)
      atomicAdd(&hist[tmp[i] >> 24], 1);
    __syncthreads();
    int v = hist[t];
    scn[t] = v; __syncthreads();
    int acc = v;
    for (int o = 1; o < 256; o <<= 1) {
      int u = (t >= o) ? scn[t - o] : 0;
      __syncthreads();
      acc += u; scn[t] = acc;
      __syncthreads();
    }
    int ex = acc - v;
    cursor[t] = ex;
    int d = bin * 256 + t;
    if (d < a.ra.N[y]) { a.ra.cnt[y][d] = v; a.ra.rs[y][d] = base + ex; }
    __syncthreads();
    int* bkt = a.ra.bkt[y];
    for (int i = base + t; i < end; i += 256) {
      unsigned int p = tmp[i];
      int pos = atomicAdd(&cursor[p >> 24], 1);
      bkt[base + pos] = (int)((p & 0xFFFFFFu) << 8);  // BYTE offset: src * 256
    }
    return;
  }
  bid -= a.p2Blocks;
  if (bid < 80) {
    // ---- weight rearrange: wf[((kc*CF+cf)*64+lane)*8+i] = W[k][c] ----
    int widx = bid >> 3;
    int OUTi = (widx < 5) ? 128 : 64;
    int CF = OUTi / 16;
    int nt = 4 * CF * 64;
    int tg = (bid & 7) * 256 + t;
    if (tg >= nt) return;
    int lane = tg & 63, tmp2 = tg >> 6;
    int cf = tmp2 % CF, kc = tmp2 / CF;
    int k0 = kc * 32 + (lane >> 4) * 8;
    int c  = cf * 16 + (lane & 15);
    const float* w = a.wa.w[widx];
    s8v v;
    #pragma unroll
    for (int i = 0; i < 8; ++i) v[i] = (short)bf16_rne(w[(k0 + i) * OUTi + c]);
    *(reinterpret_cast<s8v*>(a.wa.wf[widx]) + tg) = v;
    return;
  }
  bid -= 80;
  // ---- fp32 -> bf16 cvt, 4 elems/thread ----
  int i = bid * 256 + t;
  const float* X; unsigned short* Y;
  if (i < a.n4p) { X = a.Xp; Y = a.Yp; }
  else { i -= a.n4p; if (i >= a.n4a) return; X = a.Xa; Y = a.Ya; }
  float4 f = reinterpret_cast<const float4*>(X)[i];
  ushort4 o;
  o.x = bf16_rne(f.x); o.y = bf16_rne(f.y); o.z = bf16_rne(f.z); o.w = bf16_rne(f.w);
  reinterpret_cast<ushort4*>(Y)[i] = o;
}

// ==== gather-max: 16 lanes/row (dwordx4), 4 rows/wave, 16 rows/block, 3-way y ====
struct G3Args {
  const int* cnt[3]; const int* rs[3]; const int* bkt[3];
  const unsigned short* X[3]; unsigned short* S[3];
  int N[3];
};

__global__ __launch_bounds__(256) void gather3_k(G3Args a) {
  const int y = blockIdx.y;
  const int lane = threadIdx.x & 63;
  const int wave = threadIdx.x >> 6;
  const int g = lane >> 4, lg = lane & 15;
  const int d = blockIdx.x * 16 + wave * 4 + g;
  if (d >= a.N[y]) return;

  unsigned short* So = a.S[y] + (size_t)d * DI + lg * 8;
  const int deg = a.cnt[y][d];
  if (deg == 0) {
    uint4 z; z.x = z.y = z.z = z.w = 0u;
    *reinterpret_cast<uint4*>(So) = z;
    return;
  }
  const int* bp = a.bkt[y] + a.rs[y][d];
  const char* Xb = reinterpret_cast<const char*>(a.X[y]) + lg * 16;

  float ml[4], mh[4];
  #pragma unroll
  for (int j = 0; j < 4; ++j) { ml[j] = -3.4e38f; mh[j] = -3.4e38f; }

  int s0 = bp[0];
  for (int e = 0; e < deg; e += 4) {
    int s1 = (e + 1 < deg) ? bp[e + 1] : s0;   // branchless tail: re-max row 0
    int s2 = (e + 2 < deg) ? bp[e + 2] : s0;
    int s3 = (e + 3 < deg) ? bp[e + 3] : s0;
    int sn = (e + 4 < deg) ? bp[e + 4] : s0;
    uint4 r0 = *reinterpret_cast<const uint4*>(Xb + s0);
    uint4 r1 = *reinterpret_cast<const uint4*>(Xb + s1);
    uint4 r2 = *reinterpret_cast<const uint4*>(Xb + s2);
    uint4 r3 = *reinterpret_cast<const uint4*>(Xb + s3);
    unsigned int w0[4] = {r0.x, r0.y, r0.z, r0.w};
    unsigned int w1[4] = {r1.x, r1.y, r1.z, r1.w};
    unsigned int w2[4] = {r2.x, r2.y, r2.z, r2.w};
    unsigned int w3[4] = {r3.x, r3.y, r3.z, r3.w};
    #pragma unroll
    for (int j = 0; j < 4; ++j) {
      float tl = fmaxf(fmaxf(__uint_as_float(w0[j] << 16), __uint_as_float(w1[j] << 16)),
                       __uint_as_float(w2[j] << 16));
      ml[j] = fmaxf(fmaxf(ml[j], __uint_as_float(w3[j] << 16)), tl);
      // high halves: RAW word as float (low bits perturb < 1 ulp of hi bf16)
      float th = fmaxf(fmaxf(__uint_as_float(w0[j]), __uint_as_float(w1[j])),
                       __uint_as_float(w2[j]));
      mh[j] = fmaxf(fmaxf(mh[j], __uint_as_float(w3[j])), th);
    }
    s0 = sn;
  }
  uint4 o;
  o.x = (__float_as_uint(ml[0]) >> 16) | (__float_as_uint(mh[0]) & 0xFFFF0000u);
  o.y = (__float_as_uint(ml[1]) >> 16) | (__float_as_uint(mh[1]) & 0xFFFF0000u);
  o.z = (__float_as_uint(ml[2]) >> 16) | (__float_as_uint(mh[2]) & 0xFFFF0000u);
  o.w = (__float_as_uint(ml[3]) >> 16) | (__float_as_uint(mh[3]) & 0xFFFF0000u);
  *reinterpret_cast<uint4*>(So) = o;
}

// ==== fused GEMM pair: paper (3-src) blocks then author (2-src) blocks ====
// MFMA 16x16x32 bf16: A row=lane&15,k=(lane>>4)*8+i; B col=lane&15; D col=lane&15,row=(lane>>4)*4+reg
template<int CF>
__device__ __forceinline__ void mfma_accum(const unsigned short* __restrict__ A,
                                           const unsigned short* __restrict__ W,
                                           f32x4* acc, size_t arow, int lane, int half) {
  const s8v* a = reinterpret_cast<const s8v*>(A + arow * DI + half * 8);
  const s8v* w = reinterpret_cast<const s8v*>(W) + lane;
  #pragma unroll
  for (int kc = 0; kc < 4; ++kc) {
    s8v av = a[kc * 4];
    #pragma unroll
    for (int cf = 0; cf < CF; ++cf)
      acc[cf] = __builtin_amdgcn_mfma_f32_16x16x32_bf16(av, w[(kc * CF + cf) * 64], acc[cf], 0, 0, 0);
  }
}

struct GemmPairArgs {
  const unsigned short *A0[2], *W0[2], *A1[2], *W1[2], *A2, *W2;
  const float* bias[2];
  void* out[2];
  int N[2];
  int blocks0;
};

template<int OUT, bool RELU, bool OUT_BF16>
__global__ __launch_bounds__(256) void gemm_pair_k(GemmPairArgs g) {
  constexpr int CF = OUT / 16;
  const int p = (blockIdx.x >= (unsigned)g.blocks0) ? 1 : 0;
  const int brow = blockIdx.x - (p ? g.blocks0 : 0);
  const int N = g.N[p];
  const int lane = threadIdx.x & 63;
  const int wave = threadIdx.x >> 6;
  const int row0 = brow * 64 + wave * 16;
  if (row0 >= N) return;
  const int rl = lane & 15, half = lane >> 4;
  const size_t arow = (size_t)(row0 + rl);

  f32x4 acc[CF];
  #pragma unroll
  for (int i = 0; i < CF; ++i) acc[i] = f32x4{0.f, 0.f, 0.f, 0.f};

  mfma_accum<CF>(g.A0[p], g.W0[p], acc, arow, lane, half);
  mfma_accum<CF>(g.A1[p], g.W1[p], acc, arow, lane, half);
  if (!p) mfma_accum<CF>(g.A2, g.W2, acc, arow, lane, half);

  const float* bias = g.bias[p];
  #pragma unroll
  for (int cf = 0; cf < CF; ++cf) {
    float bv = bias[cf * 16 + rl];
    #pragma unroll
    for (int j = 0; j < 4; ++j) {
      int r = row0 + half * 4 + j;
      if (r >= N) continue;
      float v = acc[cf][j] + bv;
      if (RELU) v = v > 0.f ? v : 0.f;
      size_t idx = (size_t)r * OUT + cf * 16 + rl;
      if (OUT_BF16) ((unsigned short*)g.out[p])[idx] = bf16_rne(v);
      else          __builtin_nontemporal_store(v, (float*)g.out[p] + idx);  // final out: never re-read
    }
  }
}

extern "C" void kernel_launch(void* const* d_in, const int* in_sizes, int n_in,
                              void* d_out, int out_size, void* d_ws, size_t ws_size,
                              hipStream_t stream) {
  const float* xp = (const float*)d_in[0];
  const float* xa = (const float*)d_in[1];
  const int* wsrc = (const int*)d_in[2];
  const int* wdst = (const int*)d_in[3];
  const int* csrc = (const int*)d_in[4];
  const int* cdst = (const int*)d_in[5];
  const int* bsrc = (const int*)d_in[6];
  const int* bdst = (const int*)d_in[7];
  const int Ew = in_sizes[2], Ec = in_sizes[4], Eb = in_sizes[6];

  const float* w1w  = (const float*)d_in[8];
  const float* w1c  = (const float*)d_in[9];
  const float* w1wb = (const float*)d_in[10];
  const float* w1rp = (const float*)d_in[11];
  const float* b1rp = (const float*)d_in[12];
  const float* w1ra = (const float*)d_in[13];
  const float* b1ra = (const float*)d_in[14];
  const float* w2w  = (const float*)d_in[15];
  const float* w2c  = (const float*)d_in[16];
  const float* w2wb = (const float*)d_in[17];
  const float* w2rp = (const float*)d_in[18];
  const float* b2rp = (const float*)d_in[19];
  const float* w2ra = (const float*)d_in[20];
  const float* b2ra = (const float*)d_in[21];

  // ---- workspace layout (bytes) ----
  char* ws = (char*)d_ws;
  unsigned short* xpb = (unsigned short*)(ws + 0);           // 25,600,000
  unsigned short* xab = (unsigned short*)(ws + 25600000);    // 12,800,000
  unsigned short* hp  = (unsigned short*)(ws + 38400000);    // 25,600,000
  unsigned short* ha  = (unsigned short*)(ws + 64000000);    // 12,800,000
  unsigned short* S_w = (unsigned short*)(ws + 76800000);    // 25,600,000
  unsigned short* S_c = (unsigned short*)(ws + 102400000);   // 25,600,000
  unsigned short* S_b = (unsigned short*)(ws + 128000000);   // 12,800,000
  int* bkt_w = (int*)(ws + 140800000);                       // 3,200,000
  int* bkt_c = (int*)(ws + 144000000);                       // 3,200,000
  int* bkt_b = (int*)(ws + 147200000);                       // 3,200,000
  int* cnt_w = (int*)(ws + 150400000);                       // 400,000
  int* cnt_c = (int*)(ws + 150800000);                       // 400,000
  int* cnt_b = (int*)(ws + 151200000);                       // 200,000
  int* rs_w  = (int*)(ws + 151400000);                       // 400,000
  int* rs_c  = (int*)(ws + 151800000);                       // 400,000
  int* rs_b  = (int*)(ws + 152200000);                       // 200,000
  unsigned short* wf = (unsigned short*)(ws + 152412288);    // 245,760
  unsigned int* tmp_w = (unsigned int*)(ws + 152660000);     // 3,200,000
  unsigned int* tmp_c = (unsigned int*)(ws + 155860000);     // 3,200,000
  unsigned int* tmp_b = (unsigned int*)(ws + 159060000);     // 3,200,000
  // bh/bhs carved from S_w region (dead until first gather, which is after p2cvt)
  int* bh_w  = (int*)(ws + 76800000);
  int* bh_c  = (int*)(ws + 77110000);
  int* bh_b  = (int*)(ws + 77420000);
  int* bhs_w = (int*)(ws + 77580000);
  int* bhs_c = (int*)(ws + 77890000);
  int* bhs_b = (int*)(ws + 78200000);

  unsigned short* WF[10];
  size_t off = 0;
  for (int i = 0; i < 10; ++i) {
    WF[i] = wf + off;
    off += (i < 5) ? (size_t)128 * 128 : (size_t)128 * 64;
  }

  float* outP = (float*)d_out;              // 100000 x 64 fp32
  float* outA = outP + (size_t)NP * 64;     // 50000 x 64 fp32

  const int gP = (NP + 63) / 64, gA = (NA + 63) / 64;  // 1563, 782
  const int gG = (NP + 15) / 16;                       // 6250

  // ---- radix CSR args ----
  R3Args ra;
  ra.src[0] = wsrc; ra.dst[0] = wdst; ra.E[0] = Ew; ra.N[0] = NP;
  ra.src[1] = csrc; ra.dst[1] = cdst; ra.E[1] = Ec; ra.N[1] = NP;
  ra.src[2] = bsrc; ra.dst[2] = bdst; ra.E[2] = Eb; ra.N[2] = NA;
  ra.bh[0] = bh_w; ra.bh[1] = bh_c; ra.bh[2] = bh_b;
  ra.bhs[0] = bhs_w; ra.bhs[1] = bhs_c; ra.bhs[2] = bhs_b;
  ra.tmp[0] = tmp_w; ra.tmp[1] = tmp_c; ra.tmp[2] = tmp_b;
  ra.bkt[0] = bkt_w; ra.bkt[1] = bkt_c; ra.bkt[2] = bkt_b;
  ra.cnt[0] = cnt_w; ra.cnt[1] = cnt_c; ra.cnt[2] = cnt_b;
  ra.rs[0] = rs_w; ra.rs[1] = rs_c; ra.rs[2] = rs_b;
  int gSX = 0, maxbin = 0;
  for (int y = 0; y < 3; ++y) {
    ra.nbin[y] = (ra.N[y] + 255) >> 8;                 // 391, 391, 196
    ra.NB[y] = (ra.E[y] + EPB - 1) / EPB;              // 49 each
    if (ra.NB[y] > gSX) gSX = ra.NB[y];
    if (ra.nbin[y] > maxbin) maxbin = ra.nbin[y];
  }
  S1Args sc;
  for (int y = 0; y < 3; ++y) {
    sc.cnt[y] = ra.bh[y]; sc.rs[y] = ra.bhs[y];
    sc.n[y] = ra.nbin[y] * ra.NB[y];                   // 19159, 19159, 9604
  }

  // ---- merged p2 + warrange + cvt args ----
  const int n4p = NP * DI / 4, n4a = NA * DI / 4;
  P2CArgs pc;
  pc.ra = ra;
  const float* wsrcs[10] = {w1w, w1c, w1wb, w1rp, w1ra, w2w, w2c, w2wb, w2rp, w2ra};
  for (int i = 0; i < 10; ++i) { pc.wa.w[i] = wsrcs[i]; pc.wa.wf[i] = WF[i]; }
  pc.Xp = xp; pc.Yp = xpb; pc.n4p = n4p;
  pc.Xa = xa; pc.Ya = xab; pc.n4a = n4a;
  pc.maxbin = maxbin;
  pc.p2Blocks = 3 * maxbin;
  const int gPC = pc.p2Blocks + 80 + (n4p + n4a + 255) / 256;

  G3Args g1, g2;
  for (int i = 0; i < 3; ++i) {
    g1.cnt[i] = g2.cnt[i] = (i == 0) ? cnt_w : (i == 1) ? cnt_c : cnt_b;
    g1.rs[i]  = g2.rs[i]  = (i == 0) ? rs_w  : (i == 1) ? rs_c  : rs_b;
    g1.bkt[i] = g2.bkt[i] = (i == 0) ? bkt_w : (i == 1) ? bkt_c : bkt_b;
    g1.S[i]   = g2.S[i]   = (i == 0) ? S_w   : (i == 1) ? S_c   : S_b;
    g1.N[i]   = g2.N[i]   = (i == 2) ? NA : NP;
  }
  g1.X[0] = xab; g1.X[1] = xpb; g1.X[2] = xpb;
  g2.X[0] = ha;  g2.X[1] = hp;  g2.X[2] = hp;

  GemmPairArgs p1, p2;
  p1.A0[0] = xpb; p1.W0[0] = WF[3]; p1.A1[0] = S_w; p1.W1[0] = WF[0]; p1.A2 = S_c; p1.W2 = WF[1];
  p1.bias[0] = b1rp; p1.out[0] = hp; p1.N[0] = NP;
  p1.A0[1] = xab; p1.W0[1] = WF[4]; p1.A1[1] = S_b; p1.W1[1] = WF[2];
  p1.bias[1] = b1ra; p1.out[1] = ha; p1.N[1] = NA;
  p1.blocks0 = gP;
  p2.A0[0] = hp; p2.W0[0] = WF[8]; p2.A1[0] = S_w; p2.W1[0] = WF[5]; p2.A2 = S_c; p2.W2 = WF[6];
  p2.bias[0] = b2rp; p2.out[0] = outP; p2.N[0] = NP;
  p2.A0[1] = ha; p2.W0[1] = WF[9]; p2.A1[1] = S_b; p2.W1[1] = WF[7];
  p2.bias[1] = b2ra; p2.out[1] = outA; p2.N[1] = NA;
  p2.blocks0 = gP;

  // ---- CSR build + prep: 4 dispatches (no global atomics, no memsets) ----
  radix_s1_k<<<dim3(gSX, 3), 256, 0, stream>>>(ra);
  scan1_k<<<3, 1024, 0, stream>>>(sc);
  radix_x1_k<<<dim3(gSX, 3), 256, 0, stream>>>(ra);
  p2cvt_k<<<gPC, 256, 0, stream>>>(pc);   // p2 + weight rearrange + bf16 cvt

  // ---- layer 1 ----
  gather3_k<<<dim3(gG, 3), 256, 0, stream>>>(g1);
  gemm_pair_k<128, true, true><<<gP + gA, 256, 0, stream>>>(p1);

  // ---- layer 2 ----
  gather3_k<<<dim3(gG, 3), 256, 0, stream>>>(g2);
  gemm_pair_k<64, false, false><<<gP + gA, 256, 0, stream>>>(p2);
}

// Round 14
// 325.550 us; speedup vs baseline: 2.8761x; 1.1603x over previous
//
#include <hip/hip_runtime.h>

// RGCN 2-layer hetero graph conv. fp32 I/O, bf16 MFMA compute.
// R14: revert R13's EPB=16384 (x1 parallelism starvation, +43us). Back to the
// proven R11 config (334.5us) with ONE cut: partials3_k dispatch dropped —
// scanwrite3_k self-computes its block offset by reducing bsum[0..blk) in LDS
// (<=75 entries, trivial). Prep: s1 -> blocksum -> scanwrite -> x1 -> p2cvt.
// Gathers at random-gather floor (~8.2 TB/s effective); GEMMs streaming-bound.

#define DI 128
#define NP 100000
#define NA 50000
#define EPB 4096
#define MAXBIN 391

typedef short s8v __attribute__((ext_vector_type(8)));
typedef float f32x4 __attribute__((ext_vector_type(4)));

__device__ __forceinline__ unsigned short bf16_rne(float f) {
  unsigned int fb = __float_as_uint(f);
  fb += 0x7FFFu + ((fb >> 16) & 1u);
  return (unsigned short)(fb >> 16);
}

// ==== radix CSR build (3 edge types via blockIdx.y) ====
struct R3Args {
  const int* src[3]; const int* dst[3];
  int* bh[3]; int* bhs[3];
  unsigned int* tmp[3];
  int* bkt[3]; int* cnt[3]; int* rs[3];
  int E[3]; int N[3]; int nbin[3]; int NB[3];
};

__global__ __launch_bounds__(256) void radix_s1_k(R3Args a) {
  int y = blockIdx.y, blk = blockIdx.x;
  int NB = a.NB[y];
  if (blk >= NB) return;
  __shared__ int hist[MAXBIN];
  int nbin = a.nbin[y];
  for (int i = threadIdx.x; i < nbin; i += 256) hist[i] = 0;
  __syncthreads();
  int e0 = blk * EPB, e1 = min(e0 + EPB, a.E[y]);
  const int* dst = a.dst[y];
  for (int e = e0 + threadIdx.x; e < e1; e += 256)
    atomicAdd(&hist[dst[e] >> 8], 1);
  __syncthreads();
  int* bh = a.bh[y];
  for (int i = threadIdx.x; i < nbin; i += 256) bh[i * NB + blk] = hist[i];
}

__global__ __launch_bounds__(256) void radix_x1_k(R3Args a) {
  int y = blockIdx.y, blk = blockIdx.x;
  int NB = a.NB[y];
  if (blk >= NB) return;
  __shared__ int cur[MAXBIN];
  int nbin = a.nbin[y];
  const int* bhs = a.bhs[y];
  for (int i = threadIdx.x; i < nbin; i += 256) cur[i] = bhs[i * NB + blk];
  __syncthreads();
  int e0 = blk * EPB, e1 = min(e0 + EPB, a.E[y]);
  const int* dst = a.dst[y];
  const int* src = a.src[y];
  unsigned int* tmp = a.tmp[y];
  for (int e = e0 + threadIdx.x; e < e1; e += 256) {
    int d = dst[e];
    int pos = atomicAdd(&cur[d >> 8], 1);
    tmp[pos] = ((unsigned int)(d & 255) << 24) | (unsigned int)src[e];
  }
}

// ==== hierarchical exclusive scan (for bh -> bhs), 2 dispatches ====
struct S3Args {
  const int* cnt[3]; int* bsum[3]; int* rs[3];
  int n[3]; int nb[3];
};

__global__ __launch_bounds__(256) void blocksum3_k(S3Args a) {
  int y = blockIdx.y;
  int n = a.n[y];
  if (blockIdx.x * 1024 >= n) return;
  __shared__ int red[256];
  int t = threadIdx.x;
  int base = blockIdx.x * 1024 + t * 4;
  int s = 0;
  #pragma unroll
  for (int i = 0; i < 4; ++i) { int idx = base + i; if (idx < n) s += a.cnt[y][idx]; }
  red[t] = s; __syncthreads();
  #pragma unroll
  for (int o = 128; o > 0; o >>= 1) { if (t < o) red[t] += red[t + o]; __syncthreads(); }
  if (t == 0) a.bsum[y][blockIdx.x] = red[0];
}

// scanwrite: self-computes block offset = sum(bsum[0..blk)) in LDS (no partials pass)
__global__ __launch_bounds__(256) void scanwrite3_k(S3Args a) {
  int y = blockIdx.y;
  int n = a.n[y];
  if (blockIdx.x * 1024 >= n) return;
  __shared__ int ts[256];
  int t = threadIdx.x;
  // block offset: reduce bsum entries strictly before this chunk (nb <= 256)
  int nb = a.nb[y];
  int bv = (t < nb && t < (int)blockIdx.x) ? a.bsum[y][t] : 0;
  ts[t] = bv; __syncthreads();
  #pragma unroll
  for (int o = 128; o > 0; o >>= 1) { if (t < o) ts[t] += ts[t + o]; __syncthreads(); }
  int blockOff = ts[0];
  __syncthreads();
  int base = blockIdx.x * 1024 + t * 4;
  int v[4]; int s = 0;
  #pragma unroll
  for (int i = 0; i < 4; ++i) { int idx = base + i; v[i] = (idx < n) ? a.cnt[y][idx] : 0; s += v[i]; }
  ts[t] = s; __syncthreads();
  int inc = s;
  for (int o = 1; o < 256; o <<= 1) {
    int u = (t >= o) ? ts[t - o] : 0;
    __syncthreads();
    inc += u; ts[t] = inc;
    __syncthreads();
  }
  int p = blockOff + inc - s;
  #pragma unroll
  for (int i = 0; i < 4; ++i) { int idx = base + i; if (idx < n) { a.rs[y][idx] = p; p += v[i]; } }
}

// ---- weight rearrange args ----
struct WArgs {
  const float* w[10];
  unsigned short* wf[10];
};

// ==== merged: radix_p2 + weight rearrange + fp32->bf16 cvt ====
struct P2CArgs {
  R3Args ra;
  WArgs wa;
  const float* Xp; unsigned short* Yp; int n4p;
  const float* Xa; unsigned short* Ya; int n4a;
  int p2Blocks;   // 3 * maxbin
  int maxbin;
};

__global__ __launch_bounds__(256) void p2cvt_k(P2CArgs a) {
  int bid = blockIdx.x;
  int t = threadIdx.x;
  if (bid < a.p2Blocks) {
    // ---- radix pass 2: per coarse bucket, LDS hist+scan of low byte ----
    int y = bid / a.maxbin, bin = bid % a.maxbin;
    if (bin >= a.ra.nbin[y]) return;
    __shared__ int hist[256], scn[256], cursor[256];
    hist[t] = 0;
    __syncthreads();
    const int* bhs = a.ra.bhs[y];
    int NB = a.ra.NB[y];
    int base = bhs[bin * NB];
    int end  = (bin + 1 < a.ra.nbin[y]) ? bhs[(bin + 1) * NB] : a.ra.E[y];
    const unsigned int* tmp = a.ra.tmp[y];
    for (int i = base + t; i < end; i += 256)
      atomicAdd(&hist[tmp[i] >> 24], 1);
    __syncthreads();
    int v = hist[t];
    scn[t] = v; __syncthreads();
    int acc = v;
    for (int o = 1; o < 256; o <<= 1) {
      int u = (t >= o) ? scn[t - o] : 0;
      __syncthreads();
      acc += u; scn[t] = acc;
      __syncthreads();
    }
    int ex = acc - v;
    cursor[t] = ex;
    int d = bin * 256 + t;
    if (d < a.ra.N[y]) { a.ra.cnt[y][d] = v; a.ra.rs[y][d] = base + ex; }
    __syncthreads();
    int* bkt = a.ra.bkt[y];
    for (int i = base + t; i < end; i += 256) {
      unsigned int p = tmp[i];
      int pos = atomicAdd(&cursor[p >> 24], 1);
      bkt[base + pos] = (int)((p & 0xFFFFFFu) << 8);  // BYTE offset: src * 256
    }
    return;
  }
  bid -= a.p2Blocks;
  if (bid < 80) {
    // ---- weight rearrange: wf[((kc*CF+cf)*64+lane)*8+i] = W[k][c] ----
    int widx = bid >> 3;
    int OUTi = (widx < 5) ? 128 : 64;
    int CF = OUTi / 16;
    int nt = 4 * CF * 64;
    int tg = (bid & 7) * 256 + t;
    if (tg >= nt) return;
    int lane = tg & 63, tmp2 = tg >> 6;
    int cf = tmp2 % CF, kc = tmp2 / CF;
    int k0 = kc * 32 + (lane >> 4) * 8;
    int c  = cf * 16 + (lane & 15);
    const float* w = a.wa.w[widx];
    s8v v;
    #pragma unroll
    for (int i = 0; i < 8; ++i) v[i] = (short)bf16_rne(w[(k0 + i) * OUTi + c]);
    *(reinterpret_cast<s8v*>(a.wa.wf[widx]) + tg) = v;
    return;
  }
  bid -= 80;
  // ---- fp32 -> bf16 cvt, 4 elems/thread ----
  int i = bid * 256 + t;
  const float* X; unsigned short* Y;
  if (i < a.n4p) { X = a.Xp; Y = a.Yp; }
  else { i -= a.n4p; if (i >= a.n4a) return; X = a.Xa; Y = a.Ya; }
  float4 f = reinterpret_cast<const float4*>(X)[i];
  ushort4 o;
  o.x = bf16_rne(f.x); o.y = bf16_rne(f.y); o.z = bf16_rne(f.z); o.w = bf16_rne(f.w);
  reinterpret_cast<ushort4*>(Y)[i] = o;
}

// ==== gather-max: 16 lanes/row (dwordx4), 4 rows/wave, 16 rows/block, 3-way y ====
struct G3Args {
  const int* cnt[3]; const int* rs[3]; const int* bkt[3];
  const unsigned short* X[3]; unsigned short* S[3];
  int N[3];
};

__global__ __launch_bounds__(256) void gather3_k(G3Args a) {
  const int y = blockIdx.y;
  const int lane = threadIdx.x & 63;
  const int wave = threadIdx.x >> 6;
  const int g = lane >> 4, lg = lane & 15;
  const int d = blockIdx.x * 16 + wave * 4 + g;
  if (d >= a.N[y]) return;

  unsigned short* So = a.S[y] + (size_t)d * DI + lg * 8;
  const int deg = a.cnt[y][d];
  if (deg == 0) {
    uint4 z; z.x = z.y = z.z = z.w = 0u;
    *reinterpret_cast<uint4*>(So) = z;
    return;
  }
  const int* bp = a.bkt[y] + a.rs[y][d];
  const char* Xb = reinterpret_cast<const char*>(a.X[y]) + lg * 16;

  float ml[4], mh[4];
  #pragma unroll
  for (int j = 0; j < 4; ++j) { ml[j] = -3.4e38f; mh[j] = -3.4e38f; }

  int s0 = bp[0];
  for (int e = 0; e < deg; e += 4) {
    int s1 = (e + 1 < deg) ? bp[e + 1] : s0;   // branchless tail: re-max row 0
    int s2 = (e + 2 < deg) ? bp[e + 2] : s0;
    int s3 = (e + 3 < deg) ? bp[e + 3] : s0;
    int sn = (e + 4 < deg) ? bp[e + 4] : s0;
    uint4 r0 = *reinterpret_cast<const uint4*>(Xb + s0);
    uint4 r1 = *reinterpret_cast<const uint4*>(Xb + s1);
    uint4 r2 = *reinterpret_cast<const uint4*>(Xb + s2);
    uint4 r3 = *reinterpret_cast<const uint4*>(Xb + s3);
    unsigned int w0[4] = {r0.x, r0.y, r0.z, r0.w};
    unsigned int w1[4] = {r1.x, r1.y, r1.z, r1.w};
    unsigned int w2[4] = {r2.x, r2.y, r2.z, r2.w};
    unsigned int w3[4] = {r3.x, r3.y, r3.z, r3.w};
    #pragma unroll
    for (int j = 0; j < 4; ++j) {
      float tl = fmaxf(fmaxf(__uint_as_float(w0[j] << 16), __uint_as_float(w1[j] << 16)),
                       __uint_as_float(w2[j] << 16));
      ml[j] = fmaxf(fmaxf(ml[j], __uint_as_float(w3[j] << 16)), tl);
      // high halves: RAW word as float (low bits perturb < 1 ulp of hi bf16)
      float th = fmaxf(fmaxf(__uint_as_float(w0[j]), __uint_as_float(w1[j])),
                       __uint_as_float(w2[j]));
      mh[j] = fmaxf(fmaxf(mh[j], __uint_as_float(w3[j])), th);
    }
    s0 = sn;
  }
  uint4 o;
  o.x = (__float_as_uint(ml[0]) >> 16) | (__float_as_uint(mh[0]) & 0xFFFF0000u);
  o.y = (__float_as_uint(ml[1]) >> 16) | (__float_as_uint(mh[1]) & 0xFFFF0000u);
  o.z = (__float_as_uint(ml[2]) >> 16) | (__float_as_uint(mh[2]) & 0xFFFF0000u);
  o.w = (__float_as_uint(ml[3]) >> 16) | (__float_as_uint(mh[3]) & 0xFFFF0000u);
  *reinterpret_cast<uint4*>(So) = o;
}

// ==== fused GEMM pair: paper (3-src) blocks then author (2-src) blocks ====
// MFMA 16x16x32 bf16: A row=lane&15,k=(lane>>4)*8+i; B col=lane&15; D col=lane&15,row=(lane>>4)*4+reg
template<int CF>
__device__ __forceinline__ void mfma_accum(const unsigned short* __restrict__ A,
                                           const unsigned short* __restrict__ W,
                                           f32x4* acc, size_t arow, int lane, int half) {
  const s8v* a = reinterpret_cast<const s8v*>(A + arow * DI + half * 8);
  const s8v* w = reinterpret_cast<const s8v*>(W) + lane;
  #pragma unroll
  for (int kc = 0; kc < 4; ++kc) {
    s8v av = a[kc * 4];
    #pragma unroll
    for (int cf = 0; cf < CF; ++cf)
      acc[cf] = __builtin_amdgcn_mfma_f32_16x16x32_bf16(av, w[(kc * CF + cf) * 64], acc[cf], 0, 0, 0);
  }
}

struct GemmPairArgs {
  const unsigned short *A0[2], *W0[2], *A1[2], *W1[2], *A2, *W2;
  const float* bias[2];
  void* out[2];
  int N[2];
  int blocks0;
};

template<int OUT, bool RELU, bool OUT_BF16>
__global__ __launch_bounds__(256) void gemm_pair_k(GemmPairArgs g) {
  constexpr int CF = OUT / 16;
  const int p = (blockIdx.x >= (unsigned)g.blocks0) ? 1 : 0;
  const int brow = blockIdx.x - (p ? g.blocks0 : 0);
  const int N = g.N[p];
  const int lane = threadIdx.x & 63;
  const int wave = threadIdx.x >> 6;
  const int row0 = brow * 64 + wave * 16;
  if (row0 >= N) return;
  const int rl = lane & 15, half = lane >> 4;
  const size_t arow = (size_t)(row0 + rl);

  f32x4 acc[CF];
  #pragma unroll
  for (int i = 0; i < CF; ++i) acc[i] = f32x4{0.f, 0.f, 0.f, 0.f};

  mfma_accum<CF>(g.A0[p], g.W0[p], acc, arow, lane, half);
  mfma_accum<CF>(g.A1[p], g.W1[p], acc, arow, lane, half);
  if (!p) mfma_accum<CF>(g.A2, g.W2, acc, arow, lane, half);

  const float* bias = g.bias[p];
  #pragma unroll
  for (int cf = 0; cf < CF; ++cf) {
    float bv = bias[cf * 16 + rl];
    #pragma unroll
    for (int j = 0; j < 4; ++j) {
      int r = row0 + half * 4 + j;
      if (r >= N) continue;
      float v = acc[cf][j] + bv;
      if (RELU) v = v > 0.f ? v : 0.f;
      size_t idx = (size_t)r * OUT + cf * 16 + rl;
      if (OUT_BF16) ((unsigned short*)g.out[p])[idx] = bf16_rne(v);
      else          __builtin_nontemporal_store(v, (float*)g.out[p] + idx);  // final out: never re-read
    }
  }
}

extern "C" void kernel_launch(void* const* d_in, const int* in_sizes, int n_in,
                              void* d_out, int out_size, void* d_ws, size_t ws_size,
                              hipStream_t stream) {
  const float* xp = (const float*)d_in[0];
  const float* xa = (const float*)d_in[1];
  const int* wsrc = (const int*)d_in[2];
  const int* wdst = (const int*)d_in[3];
  const int* csrc = (const int*)d_in[4];
  const int* cdst = (const int*)d_in[5];
  const int* bsrc = (const int*)d_in[6];
  const int* bdst = (const int*)d_in[7];
  const int Ew = in_sizes[2], Ec = in_sizes[4], Eb = in_sizes[6];

  const float* w1w  = (const float*)d_in[8];
  const float* w1c  = (const float*)d_in[9];
  const float* w1wb = (const float*)d_in[10];
  const float* w1rp = (const float*)d_in[11];
  const float* b1rp = (const float*)d_in[12];
  const float* w1ra = (const float*)d_in[13];
  const float* b1ra = (const float*)d_in[14];
  const float* w2w  = (const float*)d_in[15];
  const float* w2c  = (const float*)d_in[16];
  const float* w2wb = (const float*)d_in[17];
  const float* w2rp = (const float*)d_in[18];
  const float* b2rp = (const float*)d_in[19];
  const float* w2ra = (const float*)d_in[20];
  const float* b2ra = (const float*)d_in[21];

  // ---- workspace layout (bytes) ----
  char* ws = (char*)d_ws;
  unsigned short* xpb = (unsigned short*)(ws + 0);           // 25,600,000
  unsigned short* xab = (unsigned short*)(ws + 25600000);    // 12,800,000
  unsigned short* hp  = (unsigned short*)(ws + 38400000);    // 25,600,000
  unsigned short* ha  = (unsigned short*)(ws + 64000000);    // 12,800,000
  unsigned short* S_w = (unsigned short*)(ws + 76800000);    // 25,600,000
  unsigned short* S_c = (unsigned short*)(ws + 102400000);   // 25,600,000
  unsigned short* S_b = (unsigned short*)(ws + 128000000);   // 12,800,000
  int* bkt_w = (int*)(ws + 140800000);                       // 3,200,000
  int* bkt_c = (int*)(ws + 144000000);                       // 3,200,000
  int* bkt_b = (int*)(ws + 147200000);                       // 3,200,000
  int* cnt_w = (int*)(ws + 150400000);                       // 400,000
  int* cnt_c = (int*)(ws + 150800000);                       // 400,000
  int* cnt_b = (int*)(ws + 151200000);                       // 200,000
  int* rs_w  = (int*)(ws + 151400000);                       // 400,000
  int* rs_c  = (int*)(ws + 151800000);                       // 400,000
  int* rs_b  = (int*)(ws + 152200000);                       // 200,000
  int* bsum_w = (int*)(ws + 152400000);                      // 4,096
  int* bsum_c = (int*)(ws + 152404096);                      // 4,096
  int* bsum_b = (int*)(ws + 152408192);                      // 4,096
  unsigned short* wf = (unsigned short*)(ws + 152412288);    // 245,760
  unsigned int* tmp_w = (unsigned int*)(ws + 152660000);     // 3,200,000
  unsigned int* tmp_c = (unsigned int*)(ws + 155860000);     // 3,200,000
  unsigned int* tmp_b = (unsigned int*)(ws + 159060000);     // 3,200,000
  // bh/bhs carved from S_w region (dead until first gather, which is after p2cvt)
  int* bh_w  = (int*)(ws + 76800000);
  int* bh_c  = (int*)(ws + 77110000);
  int* bh_b  = (int*)(ws + 77420000);
  int* bhs_w = (int*)(ws + 77580000);
  int* bhs_c = (int*)(ws + 77890000);
  int* bhs_b = (int*)(ws + 78200000);

  unsigned short* WF[10];
  size_t off = 0;
  for (int i = 0; i < 10; ++i) {
    WF[i] = wf + off;
    off += (i < 5) ? (size_t)128 * 128 : (size_t)128 * 64;
  }

  float* outP = (float*)d_out;              // 100000 x 64 fp32
  float* outA = outP + (size_t)NP * 64;     // 50000 x 64 fp32

  const int gP = (NP + 63) / 64, gA = (NA + 63) / 64;  // 1563, 782
  const int gG = (NP + 15) / 16;                       // 6250

  // ---- radix CSR args ----
  R3Args ra;
  ra.src[0] = wsrc; ra.dst[0] = wdst; ra.E[0] = Ew; ra.N[0] = NP;
  ra.src[1] = csrc; ra.dst[1] = cdst; ra.E[1] = Ec; ra.N[1] = NP;
  ra.src[2] = bsrc; ra.dst[2] = bdst; ra.E[2] = Eb; ra.N[2] = NA;
  ra.bh[0] = bh_w; ra.bh[1] = bh_c; ra.bh[2] = bh_b;
  ra.bhs[0] = bhs_w; ra.bhs[1] = bhs_c; ra.bhs[2] = bhs_b;
  ra.tmp[0] = tmp_w; ra.tmp[1] = tmp_c; ra.tmp[2] = tmp_b;
  ra.bkt[0] = bkt_w; ra.bkt[1] = bkt_c; ra.bkt[2] = bkt_b;
  ra.cnt[0] = cnt_w; ra.cnt[1] = cnt_c; ra.cnt[2] = cnt_b;
  ra.rs[0] = rs_w; ra.rs[1] = rs_c; ra.rs[2] = rs_b;
  int gSX = 0, gSC = 0, maxbin = 0;
  for (int y = 0; y < 3; ++y) {
    ra.nbin[y] = (ra.N[y] + 255) >> 8;                 // 391, 391, 196
    ra.NB[y] = (ra.E[y] + EPB - 1) / EPB;              // 196 each
    if (ra.NB[y] > gSX) gSX = ra.NB[y];
    if (ra.nbin[y] > maxbin) maxbin = ra.nbin[y];
  }
  S3Args sa;
  sa.bsum[0] = bsum_w; sa.bsum[1] = bsum_c; sa.bsum[2] = bsum_b;
  for (int y = 0; y < 3; ++y) {
    sa.cnt[y] = ra.bh[y]; sa.rs[y] = ra.bhs[y];
    sa.n[y] = ra.nbin[y] * ra.NB[y];                   // 76636, 76636, 38416
    sa.nb[y] = (sa.n[y] + 1023) / 1024;                // 75, 75, 38
    if (sa.nb[y] > gSC) gSC = sa.nb[y];
  }

  // ---- merged p2 + warrange + cvt args ----
  const int n4p = NP * DI / 4, n4a = NA * DI / 4;
  P2CArgs pc;
  pc.ra = ra;
  const float* wsrcs[10] = {w1w, w1c, w1wb, w1rp, w1ra, w2w, w2c, w2wb, w2rp, w2ra};
  for (int i = 0; i < 10; ++i) { pc.wa.w[i] = wsrcs[i]; pc.wa.wf[i] = WF[i]; }
  pc.Xp = xp; pc.Yp = xpb; pc.n4p = n4p;
  pc.Xa = xa; pc.Ya = xab; pc.n4a = n4a;
  pc.maxbin = maxbin;
  pc.p2Blocks = 3 * maxbin;
  const int gPC = pc.p2Blocks + 80 + (n4p + n4a + 255) / 256;

  G3Args g1, g2;
  for (int i = 0; i < 3; ++i) {
    g1.cnt[i] = g2.cnt[i] = (i == 0) ? cnt_w : (i == 1) ? cnt_c : cnt_b;
    g1.rs[i]  = g2.rs[i]  = (i == 0) ? rs_w  : (i == 1) ? rs_c  : rs_b;
    g1.bkt[i] = g2.bkt[i] = (i == 0) ? bkt_w : (i == 1) ? bkt_c : bkt_b;
    g1.S[i]   = g2.S[i]   = (i == 0) ? S_w   : (i == 1) ? S_c   : S_b;
    g1.N[i]   = g2.N[i]   = (i == 2) ? NA : NP;
  }
  g1.X[0] = xab; g1.X[1] = xpb; g1.X[2] = xpb;
  g2.X[0] = ha;  g2.X[1] = hp;  g2.X[2] = hp;

  GemmPairArgs p1, p2;
  p1.A0[0] = xpb; p1.W0[0] = WF[3]; p1.A1[0] = S_w; p1.W1[0] = WF[0]; p1.A2 = S_c; p1.W2 = WF[1];
  p1.bias[0] = b1rp; p1.out[0] = hp; p1.N[0] = NP;
  p1.A0[1] = xab; p1.W0[1] = WF[4]; p1.A1[1] = S_b; p1.W1[1] = WF[2];
  p1.bias[1] = b1ra; p1.out[1] = ha; p1.N[1] = NA;
  p1.blocks0 = gP;
  p2.A0[0] = hp; p2.W0[0] = WF[8]; p2.A1[0] = S_w; p2.W1[0] = WF[5]; p2.A2 = S_c; p2.W2 = WF[6];
  p2.bias[0] = b2rp; p2.out[0] = outP; p2.N[0] = NP;
  p2.A0[1] = ha; p2.W0[1] = WF[9]; p2.A1[1] = S_b; p2.W1[1] = WF[7];
  p2.bias[1] = b2ra; p2.out[1] = outA; p2.N[1] = NA;
  p2.blocks0 = gP;

  // ---- CSR build + prep: 5 dispatches (no global atomics, no memsets) ----
  radix_s1_k<<<dim3(gSX, 3), 256, 0, stream>>>(ra);
  blocksum3_k<<<dim3(gSC, 3), 256, 0, stream>>>(sa);
  scanwrite3_k<<<dim3(gSC, 3), 256, 0, stream>>>(sa);
  radix_x1_k<<<dim3(gSX, 3), 256, 0, stream>>>(ra);
  p2cvt_k<<<gPC, 256, 0, stream>>>(pc);   // p2 + weight rearrange + bf16 cvt

  // ---- layer 1 ----
  gather3_k<<<dim3(gG, 3), 256, 0, stream>>>(g1);
  gemm_pair_k<128, true, true><<<gP + gA, 256, 0, stream>>>(p1);

  // ---- layer 2 ----
  gather3_k<<<dim3(gG, 3), 256, 0, stream>>>(g2);
  gemm_pair_k<64, false, false><<<gP + gA, 256, 0, stream>>>(p2);
}